// Round 2
// baseline (242.783 us; speedup 1.0000x reference)
//
#include <hip/hip_runtime.h>

#define KDIM 1024

typedef __attribute__((ext_vector_type(8))) short bf16x8;
typedef __attribute__((ext_vector_type(4))) short short4v;
typedef __attribute__((ext_vector_type(4))) float f32x4;

__device__ __forceinline__ short f2bf(float f) {
    union { float f; unsigned u; } x; x.f = f;
    unsigned r = x.u + 0x7fffu + ((x.u >> 16) & 1u);   // RNE
    return (short)(r >> 16);
}

// 8x fp32 -> bf16x8 via v_cvt_pk_bf16_f32 (RNE on gfx950)
__device__ __forceinline__ bf16x8 cvt8(f32x4 a, f32x4 b) {
    union { unsigned u[4]; bf16x8 v; } r;
    asm("v_cvt_pk_bf16_f32 %0, %1, %2" : "=v"(r.u[0]) : "v"(a.x), "v"(a.y));
    asm("v_cvt_pk_bf16_f32 %0, %1, %2" : "=v"(r.u[1]) : "v"(a.z), "v"(a.w));
    asm("v_cvt_pk_bf16_f32 %0, %1, %2" : "=v"(r.u[2]) : "v"(b.x), "v"(b.y));
    asm("v_cvt_pk_bf16_f32 %0, %1, %2" : "=v"(r.u[3]) : "v"(b.z), "v"(b.w));
    return r.v;
}

// C[m][n] = sum_k A[m][k] * W[n][k] (+bias). M=256, K=1024 fixed, tile N = 32*NF.
// A: bf16 pre-fragmented: elem (m,k) at ((mf*32+kf)*64 + g*16 + r)*8 + e
//    (mf=m>>4, r=m&15, kf=k>>5, g=(k>>3)&3, e=k&7)
// W: fp32 [N][1024] row-major, read as per-lane B-fragments straight from global
//    (no LDS, no barriers), converted to bf16 in-register.
// 256 thr = 4 waves as 2M x 2N; per wave 8 m-frags x NF n-frags.
template<int NF, bool PRED>
__launch_bounds__(256, 2)
__global__ void gemm_direct(const short* __restrict__ A0, const float* __restrict__ W0,
                            float* __restrict__ C0, int nb0,
                            const short* __restrict__ A1, const float* __restrict__ W1,
                            float* __restrict__ C1,
                            const float* __restrict__ bias, int N, int ldc)
{
    const int bx = blockIdx.x;
    const short* A; const float* W; float* C; int n0;
    if (bx < nb0) { A = A0; W = W0; C = C0; n0 = bx * (32 * NF); }
    else          { A = A1; W = W1; C = C1; n0 = (bx - nb0) * (32 * NF); }

    const int t = threadIdx.x;
    const int lane = t & 63;
    const int wid = t >> 6;
    const int wr = wid >> 1;
    const int wc = wid & 1;

    // per-lane W fragment base pointers: row = col, k-offset = (lane>>4)*8
    const float* wp[NF];
    #pragma unroll
    for (int nf = 0; nf < NF; ++nf) {
        int col = n0 + (wc * NF + nf) * 16 + (lane & 15);
        if (PRED) col = (col < N) ? col : (N - 1);
        wp[nf] = W + (size_t)col * KDIM + ((lane >> 4) << 3);
    }
    // A base: + mf*16384 + s*512 + (lane*8 folded in)
    const short* ap = A + (size_t)(wr * 8) * 16384 + lane * 8;

    f32x4 acc[8][NF];
    #pragma unroll
    for (int i = 0; i < 8; ++i)
        #pragma unroll
        for (int j = 0; j < NF; ++j)
            acc[i][j] = (f32x4){0.f, 0.f, 0.f, 0.f};

    f32x4 wbuf[2][NF][2];
    bf16x8 abuf[8];

    // prologue: W(0) into buffer 0
    #pragma unroll
    for (int nf = 0; nf < NF; ++nf) {
        wbuf[0][nf][0] = *(const f32x4*)(wp[nf]);
        wbuf[0][nf][1] = *(const f32x4*)(wp[nf] + 4);
    }

#define STEP(S, CUR, NXT) do {                                                   \
    int sp_ = ((S) + 1 < 32) ? (S) + 1 : 31;                                     \
    _Pragma("unroll")                                                            \
    for (int nf = 0; nf < NF; ++nf) {                                            \
        wbuf[NXT][nf][0] = *(const f32x4*)(wp[nf] + sp_ * 32);                   \
        wbuf[NXT][nf][1] = *(const f32x4*)(wp[nf] + sp_ * 32 + 4);               \
    }                                                                            \
    _Pragma("unroll")                                                            \
    for (int mf = 0; mf < 8; ++mf)                                               \
        abuf[mf] = *(const bf16x8*)(ap + mf * 16384 + (S) * 512);                \
    bf16x8 bfr_[NF];                                                             \
    _Pragma("unroll")                                                            \
    for (int nf = 0; nf < NF; ++nf)                                              \
        bfr_[nf] = cvt8(wbuf[CUR][nf][0], wbuf[CUR][nf][1]);                     \
    _Pragma("unroll")                                                            \
    for (int mf = 0; mf < 8; ++mf) {                                             \
        _Pragma("unroll")                                                        \
        for (int nf = 0; nf < NF; ++nf)                                          \
            acc[mf][nf] = __builtin_amdgcn_mfma_f32_16x16x32_bf16(               \
                abuf[mf], bfr_[nf], acc[mf][nf], 0, 0, 0);                       \
    }                                                                            \
} while (0)

    for (int s = 0; s < 32; s += 2) {
        STEP(s, 0, 1);
        STEP(s + 1, 1, 0);
    }
#undef STEP

    // epilogue: C/D layout col = lane&15, row = (lane>>4)*4 + reg
    #pragma unroll
    for (int mf = 0; mf < 8; ++mf) {
        int row = wr * 128 + mf * 16 + ((lane >> 4) << 2);
        #pragma unroll
        for (int nf = 0; nf < NF; ++nf) {
            int col = n0 + (wc * NF + nf) * 16 + (lane & 15);
            if (PRED && col >= N) continue;
            float bv = bias ? bias[col] : 0.0f;
            #pragma unroll
            for (int r = 0; r < 4; ++r)
                C[(size_t)(row + r) * ldc + col] = acc[mf][nf][r] + bv;
        }
    }
}

// Gather embedding row / convert hidden rows into bf16 fragment layout.
__global__ void prep_kernel(const int* __restrict__ ids, const float* __restrict__ hidden,
                            const float* __restrict__ emb,
                            short* __restrict__ x_frag, short* __restrict__ h_frag)
{
    const int m = blockIdx.x;        // 0..255
    const int which = blockIdx.y;    // 0: emb gather -> x, 1/2: hidden layer
    const int j = threadIdx.x << 3;  // 128 threads * 8 elems

    const float* src;
    short* dst;
    if (which == 0) { src = emb + (size_t)ids[m] * KDIM; dst = x_frag; }
    else {
        src = hidden + ((size_t)(which - 1) * 256 + m) * KDIM;
        dst = h_frag + (size_t)(which - 1) * 256 * KDIM;
    }
    f32x4 v0 = *(const f32x4*)(src + j);
    f32x4 v1 = *(const f32x4*)(src + j + 4);
    int mf = m >> 4, rr = m & 15, kf = j >> 5, g = (j >> 3) & 3;
    short* p = dst + (size_t)((mf * 32 + kf) * 64 + g * 16 + rr) * 8;
    short4v a, b;
    a.x = f2bf(v0.x); a.y = f2bf(v0.y); a.z = f2bf(v0.z); a.w = f2bf(v0.w);
    b.x = f2bf(v1.x); b.y = f2bf(v1.y); b.z = f2bf(v1.z); b.w = f2bf(v1.w);
    *(short4v*)p = a;
    *(short4v*)(p + 4) = b;
}

// GRU gates: h_new = (1-z)*n + z*h ; writes fp32 hidden_out and bf16 x fragments.
__global__ void gate_kernel(const float* __restrict__ gi, const float* __restrict__ gh,
                            const float* __restrict__ bi, const float* __restrict__ bh,
                            const float* __restrict__ hprev, float* __restrict__ hout,
                            short* __restrict__ x_frag)
{
    const int m = blockIdx.x;
    const int j = threadIdx.x << 3;
    const float* gim = gi + (size_t)m * 3072;
    const float* ghm = gh + (size_t)m * 3072;
    const float* hp = hprev + (size_t)m * KDIM;
    float* ho = hout + (size_t)m * KDIM;
    int mf = m >> 4, rr = m & 15, kf = j >> 5, g = (j >> 3) & 3;
    short* xp = x_frag + (size_t)((mf * 32 + kf) * 64 + g * 16 + rr) * 8;

    #pragma unroll
    for (int half = 0; half < 2; ++half) {
        int jj = j + half * 4;
        f32x4 vir = *(const f32x4*)(gim + jj);
        f32x4 viz = *(const f32x4*)(gim + 1024 + jj);
        f32x4 vin = *(const f32x4*)(gim + 2048 + jj);
        f32x4 vhr = *(const f32x4*)(ghm + jj);
        f32x4 vhz = *(const f32x4*)(ghm + 1024 + jj);
        f32x4 vhn = *(const f32x4*)(ghm + 2048 + jj);
        f32x4 bir = *(const f32x4*)(bi + jj);
        f32x4 biz = *(const f32x4*)(bi + 1024 + jj);
        f32x4 bin = *(const f32x4*)(bi + 2048 + jj);
        f32x4 bhr = *(const f32x4*)(bh + jj);
        f32x4 bhz = *(const f32x4*)(bh + 1024 + jj);
        f32x4 bhn = *(const f32x4*)(bh + 2048 + jj);
        f32x4 vh  = *(const f32x4*)(hp + jj);
        f32x4 outv;
        short4v xb;
        #pragma unroll
        for (int e = 0; e < 4; ++e) {
            float r = 1.f / (1.f + __expf(-(vir[e] + bir[e] + vhr[e] + bhr[e])));
            float z = 1.f / (1.f + __expf(-(viz[e] + biz[e] + vhz[e] + bhz[e])));
            float n = tanhf(vin[e] + bin[e] + r * (vhn[e] + bhn[e]));
            outv[e] = (1.f - z) * n + z * vh[e];
        }
        *(f32x4*)(ho + jj) = outv;
        xb.x = f2bf(outv[0]); xb.y = f2bf(outv[1]); xb.z = f2bf(outv[2]); xb.w = f2bf(outv[3]);
        *(short4v*)(xp + half * 4) = xb;
    }
}

extern "C" void kernel_launch(void* const* d_in, const int* in_sizes, int n_in,
                              void* d_out, int out_size, void* d_ws, size_t ws_size,
                              hipStream_t stream)
{
    const int*   ids    = (const int*)d_in[0];
    const float* hidden = (const float*)d_in[1];
    const float* emb    = (const float*)d_in[2];
    const float* w_ih   = (const float*)d_in[3];
    const float* w_hh   = (const float*)d_in[4];
    const float* b_ih   = (const float*)d_in[5];
    const float* b_hh   = (const float*)d_in[6];
    const float* dec_w  = (const float*)d_in[7];
    const float* dec_b  = (const float*)d_in[8];

    float* out = (float*)d_out;
    float* logits = out;                                  // [256][50000]
    float* hidden_out = out + (size_t)256 * 50000;        // [2][256][1024]

    short* x_frag = (short*)d_ws;                         // 256*1024 bf16
    short* h_frag = x_frag + 256 * 1024;                  // 2*256*1024 bf16
    // gi/gh scratch lives in the (not yet written) logits region of d_out
    float* gi = logits;                                   // 256*3072
    float* gh = logits + (size_t)256 * 3072;              // 256*3072

    prep_kernel<<<dim3(256, 3), 128, 0, stream>>>(ids, hidden, emb, x_frag, h_frag);

    for (int l = 0; l < 2; ++l) {
        // gi: 96 blocks, gh: 96 blocks, BN=32 (NF=1)
        gemm_direct<1, false><<<192, 256, 0, stream>>>(
            x_frag, w_ih + (size_t)l * 3072 * 1024, gi, 96,
            h_frag + (size_t)l * 256 * 1024, w_hh + (size_t)l * 3072 * 1024, gh,
            nullptr, 3072, 3072);
        gate_kernel<<<256, 128, 0, stream>>>(
            gi, gh, b_ih + (size_t)l * 3072, b_hh + (size_t)l * 3072,
            hidden + (size_t)l * 256 * 1024,
            hidden_out + (size_t)l * 256 * 1024, x_frag);
    }

    // decoder: BN=64 (NF=2), 782 blocks over N=50000
    gemm_direct<2, true><<<782, 256, 0, stream>>>(
        x_frag, dec_w, logits, 782,
        x_frag, dec_w, logits,
        dec_b, 50000, 50000);
}

// Round 3
// 128.706 us; speedup vs baseline: 1.8863x; 1.8863x over previous
//
#include <hip/hip_runtime.h>

#define KDIM 1024

typedef __attribute__((ext_vector_type(8))) short bf16x8;
typedef __attribute__((ext_vector_type(4))) short short4v;
typedef __attribute__((ext_vector_type(4))) float f32x4;

__device__ __forceinline__ short f2bf(float f) {
    union { float f; unsigned u; } x; x.f = f;
    unsigned r = x.u + 0x7fffu + ((x.u >> 16) & 1u);   // RNE
    return (short)(r >> 16);
}

// 8x fp32 -> bf16x8 via v_cvt_pk_bf16_f32 (RNE on gfx950)
__device__ __forceinline__ bf16x8 cvt8(f32x4 a, f32x4 b) {
    union { unsigned u[4]; bf16x8 v; } r;
    asm("v_cvt_pk_bf16_f32 %0, %1, %2" : "=v"(r.u[0]) : "v"(a.x), "v"(a.y));
    asm("v_cvt_pk_bf16_f32 %0, %1, %2" : "=v"(r.u[1]) : "v"(a.z), "v"(a.w));
    asm("v_cvt_pk_bf16_f32 %0, %1, %2" : "=v"(r.u[2]) : "v"(b.x), "v"(b.y));
    asm("v_cvt_pk_bf16_f32 %0, %1, %2" : "=v"(r.u[3]) : "v"(b.z), "v"(b.w));
    return r.v;
}

__device__ __forceinline__ void gload16(const void* g, void* l) {
    __builtin_amdgcn_global_load_lds(
        (const __attribute__((address_space(1))) void*)g,
        (__attribute__((address_space(3))) void*)l, 16, 0, 0);
}

#define WAIT_VM(n) asm volatile("s_waitcnt vmcnt(" #n ")" ::: "memory")
#define BARRIER() do { asm volatile("" ::: "memory"); \
                       __builtin_amdgcn_s_barrier();  \
                       asm volatile("" ::: "memory"); } while (0)

// C[m][n] = sum_k A[m][k]*W[n][k] (+bias). M=256, K=1024, tile N = 32*NF.
// A: bf16 pre-fragmented: elem (m,k) at ((mf*32+kf)*64 + g*16 + r)*8 + e
//    (mf=m>>4, r=m&15, kf=k>>5, g=(k>>3)&3, e=k&7)
// W: fp32 [N][1024] row-major.
// Pipeline: global_load_lds DMA into a 3-buffer LDS ring, depth-2 prefetch,
// counted vmcnt (never 0 in the main loop), raw s_barrier.
// W is XOR-swizzled in LDS (chunk ^= row&7, 16B chunks) with the inverse
// swizzle applied to the per-lane GLOBAL source address (linear LDS dest).
// 256 thr = 4 waves as 2M x 2N; per wave 8 m-frags x NF n-frags.
template<int NF, bool PRED>
__launch_bounds__(256, 2)
__global__ void gemm_pipe(const short* __restrict__ A0, const float* __restrict__ W0,
                          float* __restrict__ C0, int nb0,
                          const short* __restrict__ A1, const float* __restrict__ W1,
                          float* __restrict__ C1,
                          const float* __restrict__ bias, int N, int ldc)
{
    constexpr int WBYTES = NF * 4096;        // 32*NF rows * 128B
    constexpr int BUFB   = 16384 + WBYTES;   // A slice 16KB + W slice
    __shared__ __align__(1024) char lds[3 * BUFB];

    const int bx = blockIdx.x;
    const short* A; const float* W; float* C; int n0;
    if (bx < nb0) { A = A0; W = W0; C = C0; n0 = bx * (32 * NF); }
    else          { A = A1; W = W1; C = C1; n0 = (bx - nb0) * (32 * NF); }

    const int t = threadIdx.x;
    const int lane = t & 63;
    const int w = t >> 6;
    const int wr = w >> 1;
    const int wc = w & 1;

    // --- staging address precompute (per-lane global src, wave-uniform LDS dest)
    // W: load i covers LDS slots sl=(i*4+w)*64+lane; slot sl = row*8+cc holds
    //    global chunk (cc ^ (row&7)) of row n0+row.
    const float* gW[NF];
    #pragma unroll
    for (int i = 0; i < NF; ++i) {
        int sl = (i * 4 + w) * 64 + lane;
        int row = sl >> 3, cc = sl & 7;
        int rowg = n0 + row;
        if (PRED) rowg = (rowg < N) ? rowg : (N - 1);
        gW[i] = W + (size_t)rowg * KDIM + ((cc ^ (row & 7)) << 2);
    }
    // A: load j covers mf=j*4+w chunk (1KB contiguous), lane-linear.
    const short* gA[4];
    #pragma unroll
    for (int j = 0; j < 4; ++j)
        gA[j] = A + (size_t)(j * 4 + w) * 16384 + lane * 8;

    f32x4 acc[8][NF];
    #pragma unroll
    for (int i = 0; i < 8; ++i)
        #pragma unroll
        for (int j = 0; j < NF; ++j)
            acc[i][j] = (f32x4){0.f, 0.f, 0.f, 0.f};

    auto stage = [&](int s, int buf) {
        char* base = lds + buf * BUFB;
        // W first: it's the HBM-critical stream
        #pragma unroll
        for (int i = 0; i < NF; ++i)
            gload16(gW[i] + s * 32, base + 16384 + (i * 4 + w) * 1024);
        #pragma unroll
        for (int j = 0; j < 4; ++j)
            gload16(gA[j] + s * 512, base + (j * 4 + w) * 1024);
    };

    auto compute = [&](int buf) {
        const char* base = lds + buf * BUFB;
        const char* Wb = base + 16384;
        bf16x8 bfr[NF];
        #pragma unroll
        for (int nf = 0; nf < NF; ++nf) {
            int row = (wc * NF + nf) * 16 + (lane & 15);
            int c0 = (lane >> 4) << 1;
            f32x4 lo = *(const f32x4*)(Wb + row * 128 + ((c0 ^ (row & 7)) << 4));
            f32x4 hi = *(const f32x4*)(Wb + row * 128 + (((c0 + 1) ^ (row & 7)) << 4));
            bfr[nf] = cvt8(lo, hi);
        }
        #pragma unroll
        for (int mf = 0; mf < 8; ++mf) {
            bf16x8 a = *(const bf16x8*)(base + (wr * 8 + mf) * 1024 + lane * 16);
            #pragma unroll
            for (int nf = 0; nf < NF; ++nf)
                acc[mf][nf] = __builtin_amdgcn_mfma_f32_16x16x32_bf16(a, bfr[nf], acc[mf][nf], 0, 0, 0);
        }
    };

    // prologue: two stages in flight
    stage(0, 0);
    stage(1, 1);

    int bc = 0, bp = 2;
    for (int s = 0; s < 32; ++s) {
        if (s + 2 < 32) {
            stage(s + 2, bp);
            if constexpr (NF == 2) WAIT_VM(12); else WAIT_VM(10);
        } else if (s + 2 == 32) {
            if constexpr (NF == 2) WAIT_VM(6); else WAIT_VM(5);
        } else {
            WAIT_VM(0);
        }
        BARRIER();               // stage(s) visible to all waves
        compute(bc);
        BARRIER();               // all reads of buf bc done before it's re-staged
        bc = (bc == 2) ? 0 : bc + 1;
        bp = (bp == 2) ? 0 : bp + 1;
    }

    // epilogue: C/D layout col = lane&15, row = (lane>>4)*4 + reg
    #pragma unroll
    for (int mf = 0; mf < 8; ++mf) {
        int row = wr * 128 + mf * 16 + ((lane >> 4) << 2);
        #pragma unroll
        for (int nf = 0; nf < NF; ++nf) {
            int col = n0 + (wc * NF + nf) * 16 + (lane & 15);
            if (PRED && col >= N) continue;
            float bv = bias ? bias[col] : 0.0f;
            #pragma unroll
            for (int r = 0; r < 4; ++r)
                C[(size_t)(row + r) * ldc + col] = acc[mf][nf][r] + bv;
        }
    }
}

// Gather embedding row / convert hidden rows into bf16 fragment layout.
__global__ void prep_kernel(const int* __restrict__ ids, const float* __restrict__ hidden,
                            const float* __restrict__ emb,
                            short* __restrict__ x_frag, short* __restrict__ h_frag)
{
    const int m = blockIdx.x;        // 0..255
    const int which = blockIdx.y;    // 0: emb gather -> x, 1/2: hidden layer
    const int j = threadIdx.x << 3;  // 128 threads * 8 elems

    const float* src;
    short* dst;
    if (which == 0) { src = emb + (size_t)ids[m] * KDIM; dst = x_frag; }
    else {
        src = hidden + ((size_t)(which - 1) * 256 + m) * KDIM;
        dst = h_frag + (size_t)(which - 1) * 256 * KDIM;
    }
    f32x4 v0 = *(const f32x4*)(src + j);
    f32x4 v1 = *(const f32x4*)(src + j + 4);
    int mf = m >> 4, rr = m & 15, kf = j >> 5, g = (j >> 3) & 3;
    short* p = dst + (size_t)((mf * 32 + kf) * 64 + g * 16 + rr) * 8;
    short4v a, b;
    a.x = f2bf(v0.x); a.y = f2bf(v0.y); a.z = f2bf(v0.z); a.w = f2bf(v0.w);
    b.x = f2bf(v1.x); b.y = f2bf(v1.y); b.z = f2bf(v1.z); b.w = f2bf(v1.w);
    *(short4v*)p = a;
    *(short4v*)(p + 4) = b;
}

// GRU gates: h_new = (1-z)*n + z*h ; writes fp32 hidden_out and bf16 x fragments.
__global__ void gate_kernel(const float* __restrict__ gi, const float* __restrict__ gh,
                            const float* __restrict__ bi, const float* __restrict__ bh,
                            const float* __restrict__ hprev, float* __restrict__ hout,
                            short* __restrict__ x_frag)
{
    const int m = blockIdx.x;
    const int j = threadIdx.x << 3;
    const float* gim = gi + (size_t)m * 3072;
    const float* ghm = gh + (size_t)m * 3072;
    const float* hp = hprev + (size_t)m * KDIM;
    float* ho = hout + (size_t)m * KDIM;
    int mf = m >> 4, rr = m & 15, kf = j >> 5, g = (j >> 3) & 3;
    short* xp = x_frag + (size_t)((mf * 32 + kf) * 64 + g * 16 + rr) * 8;

    #pragma unroll
    for (int half = 0; half < 2; ++half) {
        int jj = j + half * 4;
        f32x4 vir = *(const f32x4*)(gim + jj);
        f32x4 viz = *(const f32x4*)(gim + 1024 + jj);
        f32x4 vin = *(const f32x4*)(gim + 2048 + jj);
        f32x4 vhr = *(const f32x4*)(ghm + jj);
        f32x4 vhz = *(const f32x4*)(ghm + 1024 + jj);
        f32x4 vhn = *(const f32x4*)(ghm + 2048 + jj);
        f32x4 bir = *(const f32x4*)(bi + jj);
        f32x4 biz = *(const f32x4*)(bi + 1024 + jj);
        f32x4 bin = *(const f32x4*)(bi + 2048 + jj);
        f32x4 bhr = *(const f32x4*)(bh + jj);
        f32x4 bhz = *(const f32x4*)(bh + 1024 + jj);
        f32x4 bhn = *(const f32x4*)(bh + 2048 + jj);
        f32x4 vh  = *(const f32x4*)(hp + jj);
        f32x4 outv;
        short4v xb;
        #pragma unroll
        for (int e = 0; e < 4; ++e) {
            float r = 1.f / (1.f + __expf(-(vir[e] + bir[e] + vhr[e] + bhr[e])));
            float z = 1.f / (1.f + __expf(-(viz[e] + biz[e] + vhz[e] + bhz[e])));
            float n = tanhf(vin[e] + bin[e] + r * (vhn[e] + bhn[e]));
            outv[e] = (1.f - z) * n + z * vh[e];
        }
        *(f32x4*)(ho + jj) = outv;
        xb.x = f2bf(outv[0]); xb.y = f2bf(outv[1]); xb.z = f2bf(outv[2]); xb.w = f2bf(outv[3]);
        *(short4v*)(xp + half * 4) = xb;
    }
}

extern "C" void kernel_launch(void* const* d_in, const int* in_sizes, int n_in,
                              void* d_out, int out_size, void* d_ws, size_t ws_size,
                              hipStream_t stream)
{
    const int*   ids    = (const int*)d_in[0];
    const float* hidden = (const float*)d_in[1];
    const float* emb    = (const float*)d_in[2];
    const float* w_ih   = (const float*)d_in[3];
    const float* w_hh   = (const float*)d_in[4];
    const float* b_ih   = (const float*)d_in[5];
    const float* b_hh   = (const float*)d_in[6];
    const float* dec_w  = (const float*)d_in[7];
    const float* dec_b  = (const float*)d_in[8];

    float* out = (float*)d_out;
    float* logits = out;                                  // [256][50000]
    float* hidden_out = out + (size_t)256 * 50000;        // [2][256][1024]

    short* x_frag = (short*)d_ws;                         // 256*1024 bf16
    short* h_frag = x_frag + 256 * 1024;                  // 2*256*1024 bf16
    // gi/gh scratch lives in the (not yet written) logits region of d_out
    float* gi = logits;                                   // 256*3072
    float* gh = logits + (size_t)256 * 3072;              // 256*3072

    prep_kernel<<<dim3(256, 3), 128, 0, stream>>>(ids, hidden, emb, x_frag, h_frag);

    for (int l = 0; l < 2; ++l) {
        // gi: 96 blocks, gh: 96 blocks, BN=32 (NF=1)
        gemm_pipe<1, false><<<192, 256, 0, stream>>>(
            x_frag, w_ih + (size_t)l * 3072 * 1024, gi, 96,
            h_frag + (size_t)l * 256 * 1024, w_hh + (size_t)l * 3072 * 1024, gh,
            nullptr, 3072, 3072);
        gate_kernel<<<256, 128, 0, stream>>>(
            gi, gh, b_ih + (size_t)l * 3072, b_hh + (size_t)l * 3072,
            hidden + (size_t)l * 256 * 1024,
            hidden_out + (size_t)l * 256 * 1024, x_frag);
    }

    // decoder: BN=64 (NF=2), 782 blocks over N=50000
    gemm_pipe<2, true><<<782, 256, 0, stream>>>(
        x_frag, dec_w, logits, 782,
        x_frag, dec_w, logits,
        dec_b, 50000, 50000);
}

// Round 4
// 124.846 us; speedup vs baseline: 1.9447x; 1.0309x over previous
//
#include <hip/hip_runtime.h>

#define KDIM 1024

typedef __attribute__((ext_vector_type(8))) short bf16x8;
typedef __attribute__((ext_vector_type(4))) short short4v;
typedef __attribute__((ext_vector_type(4))) float f32x4;

__device__ __forceinline__ short f2bf(float f) {
    union { float f; unsigned u; } x; x.f = f;
    unsigned r = x.u + 0x7fffu + ((x.u >> 16) & 1u);   // RNE
    return (short)(r >> 16);
}

// 8x fp32 -> bf16x8 via v_cvt_pk_bf16_f32 (RNE on gfx950)
__device__ __forceinline__ bf16x8 cvt8(f32x4 a, f32x4 b) {
    union { unsigned u[4]; bf16x8 v; } r;
    asm("v_cvt_pk_bf16_f32 %0, %1, %2" : "=v"(r.u[0]) : "v"(a.x), "v"(a.y));
    asm("v_cvt_pk_bf16_f32 %0, %1, %2" : "=v"(r.u[1]) : "v"(a.z), "v"(a.w));
    asm("v_cvt_pk_bf16_f32 %0, %1, %2" : "=v"(r.u[2]) : "v"(b.x), "v"(b.y));
    asm("v_cvt_pk_bf16_f32 %0, %1, %2" : "=v"(r.u[3]) : "v"(b.z), "v"(b.w));
    return r.v;
}

__device__ __forceinline__ void gload16(const void* g, void* l) {
    __builtin_amdgcn_global_load_lds(
        (const __attribute__((address_space(1))) void*)g,
        (__attribute__((address_space(3))) void*)l, 16, 0, 0);
}

#define WAIT_VM(n) asm volatile("s_waitcnt vmcnt(" #n ")" ::: "memory")
#define BARRIER() do { asm volatile("" ::: "memory"); \
                       __builtin_amdgcn_s_barrier();  \
                       asm volatile("" ::: "memory"); } while (0)

// ---------------------------------------------------------------------------
// Decoder GEMM: C[m][n] = sum_k A[m][k]*W[n][k] + bias[n]
// M=256, K=1024, tile N = 256 per block, 196 blocks, 512 threads (8 waves).
// Wave grid: wr = w>>2 (2 m-halves of 128 rows), wc = w&3 (4 n-quarters of 64).
// Per wave: 8 m-frags x 4 n-frags of 16x16x32 MFMA; acc = 128 VGPR.
// A: bf16 pre-fragmented (elem (m,k) at ((mf*32+kf)*64 + g*16 + r)*8 + e),
//    16 KB/step, staged by gload_lds (2 instr/wave), linear layout.
// W: fp32 [N][1024] row-major, 32 KB/step staged by gload_lds (4 instr/wave)
//    into LDS layout [kc(0..3)][half(0..1)][col(0..255)] x 16B pieces ->
//    B-frag ds_read_b128 is contiguous per quarter-wave (conflict-free).
// Pipeline: 3-buffer ring, stage 2 ahead, counted vmcnt (12/6/0), 2 barriers.
// ---------------------------------------------------------------------------
__launch_bounds__(512, 1)
__global__ void gemm_dec(const short* __restrict__ A, const float* __restrict__ W,
                         float* __restrict__ C, const float* __restrict__ bias, int N)
{
    constexpr int BUFB = 49152;                 // A 16KB + W 32KB
    __shared__ __align__(1024) char lds[3 * BUFB];

    const int n0 = blockIdx.x * 256;
    const int t = threadIdx.x;
    const int lane = t & 63;
    const int w = t >> 6;       // 0..7
    const int wr = w >> 2;      // m half
    const int wc = w & 3;       // n quarter

    // --- staging source addresses ---
    // A: chunks 2w, 2w+1 (1KB each per step)
    const short* gA[2];
    #pragma unroll
    for (int i = 0; i < 2; ++i)
        gA[i] = A + (size_t)(w * 2 + i) * 16384 + lane * 8;
    // W: pieces q = w*4+i -> kc=q>>3, half=(q>>2)&1, j=q&3 ; col = j*64+lane
    const float* gW[4];
    int wdst[4];
    #pragma unroll
    for (int i = 0; i < 4; ++i) {
        int q = w * 4 + i;
        int kc = q >> 3, hf = (q >> 2) & 1, j = q & 3;
        int colg = n0 + j * 64 + lane;
        colg = (colg < N) ? colg : (N - 1);
        gW[i] = W + (size_t)colg * KDIM + kc * 8 + hf * 4;
        wdst[i] = 16384 + kc * 8192 + hf * 4096 + j * 1024;   // wave-uniform base
    }

    f32x4 acc[8][4];
    #pragma unroll
    for (int i = 0; i < 8; ++i)
        #pragma unroll
        for (int j = 0; j < 4; ++j)
            acc[i][j] = (f32x4){0.f, 0.f, 0.f, 0.f};

    auto stage = [&](int s, int buf) {
        char* base = lds + buf * BUFB;
        #pragma unroll
        for (int i = 0; i < 4; ++i)
            gload16(gW[i] + s * 32, base + wdst[i]);
        #pragma unroll
        for (int i = 0; i < 2; ++i)
            gload16(gA[i] + s * 512, base + (w * 2 + i) * 1024);
    };

    const int kc = lane >> 4;
    const int cl = lane & 15;

    auto compute = [&](int buf) {
        const char* base = lds + buf * BUFB;
        const char* Wb = base + 16384;
        bf16x8 bfr[4];
        #pragma unroll
        for (int nf = 0; nf < 4; ++nf) {
            const char* p = Wb + kc * 8192 + (wc * 64 + nf * 16 + cl) * 16;
            f32x4 lo = *(const f32x4*)(p);
            f32x4 hi = *(const f32x4*)(p + 4096);
            bfr[nf] = cvt8(lo, hi);
        }
        #pragma unroll
        for (int mf = 0; mf < 8; ++mf) {
            bf16x8 a = *(const bf16x8*)(base + (wr * 8 + mf) * 1024 + lane * 16);
            #pragma unroll
            for (int nf = 0; nf < 4; ++nf)
                acc[mf][nf] = __builtin_amdgcn_mfma_f32_16x16x32_bf16(a, bfr[nf], acc[mf][nf], 0, 0, 0);
        }
    };

    stage(0, 0);
    stage(1, 1);

    int bc = 0, bp = 2;
    for (int s = 0; s < 32; ++s) {
        if (s + 2 < 32) {
            stage(s + 2, bp);
            WAIT_VM(12);
        } else if (s + 2 == 32) {
            WAIT_VM(6);
        } else {
            WAIT_VM(0);
        }
        BARRIER();               // stage(s) visible to all waves
        compute(bc);
        BARRIER();               // buf bc fully read before it is re-staged
        bc = (bc == 2) ? 0 : bc + 1;
        bp = (bp == 2) ? 0 : bp + 1;
    }

    // epilogue: C/D layout col = lane&15, row = (lane>>4)*4 + reg
    #pragma unroll
    for (int mf = 0; mf < 8; ++mf) {
        int row = wr * 128 + mf * 16 + ((lane >> 4) << 2);
        #pragma unroll
        for (int nf = 0; nf < 4; ++nf) {
            int col = n0 + wc * 64 + nf * 16 + cl;
            if (col >= N) continue;
            float bv = bias[col];
            #pragma unroll
            for (int r = 0; r < 4; ++r)
                C[(size_t)(row + r) * N + col] = acc[mf][nf][r] + bv;
        }
    }
}

// ---------------------------------------------------------------------------
// GRU gemm (unchanged R3 structure): tile N = 32*NF, 3-buf gload_lds ring.
// ---------------------------------------------------------------------------
template<int NF, bool PRED>
__launch_bounds__(256, 2)
__global__ void gemm_pipe(const short* __restrict__ A0, const float* __restrict__ W0,
                          float* __restrict__ C0, int nb0,
                          const short* __restrict__ A1, const float* __restrict__ W1,
                          float* __restrict__ C1,
                          const float* __restrict__ bias, int N, int ldc)
{
    constexpr int WBYTES = NF * 4096;
    constexpr int BUFB   = 16384 + WBYTES;
    __shared__ __align__(1024) char lds[3 * BUFB];

    const int bx = blockIdx.x;
    const short* A; const float* W; float* C; int n0;
    if (bx < nb0) { A = A0; W = W0; C = C0; n0 = bx * (32 * NF); }
    else          { A = A1; W = W1; C = C1; n0 = (bx - nb0) * (32 * NF); }

    const int t = threadIdx.x;
    const int lane = t & 63;
    const int w = t >> 6;
    const int wr = w >> 1;
    const int wc = w & 1;

    const float* gW[NF];
    #pragma unroll
    for (int i = 0; i < NF; ++i) {
        int sl = (i * 4 + w) * 64 + lane;
        int row = sl >> 3, cc = sl & 7;
        int rowg = n0 + row;
        if (PRED) rowg = (rowg < N) ? rowg : (N - 1);
        gW[i] = W + (size_t)rowg * KDIM + ((cc ^ (row & 7)) << 2);
    }
    const short* gA[4];
    #pragma unroll
    for (int j = 0; j < 4; ++j)
        gA[j] = A + (size_t)(j * 4 + w) * 16384 + lane * 8;

    f32x4 acc[8][NF];
    #pragma unroll
    for (int i = 0; i < 8; ++i)
        #pragma unroll
        for (int j = 0; j < NF; ++j)
            acc[i][j] = (f32x4){0.f, 0.f, 0.f, 0.f};

    auto stage = [&](int s, int buf) {
        char* base = lds + buf * BUFB;
        #pragma unroll
        for (int i = 0; i < NF; ++i)
            gload16(gW[i] + s * 32, base + 16384 + (i * 4 + w) * 1024);
        #pragma unroll
        for (int j = 0; j < 4; ++j)
            gload16(gA[j] + s * 512, base + (j * 4 + w) * 1024);
    };

    auto compute = [&](int buf) {
        const char* base = lds + buf * BUFB;
        const char* Wb = base + 16384;
        bf16x8 bfr[NF];
        #pragma unroll
        for (int nf = 0; nf < NF; ++nf) {
            int row = (wc * NF + nf) * 16 + (lane & 15);
            int c0 = (lane >> 4) << 1;
            f32x4 lo = *(const f32x4*)(Wb + row * 128 + ((c0 ^ (row & 7)) << 4));
            f32x4 hi = *(const f32x4*)(Wb + row * 128 + (((c0 + 1) ^ (row & 7)) << 4));
            bfr[nf] = cvt8(lo, hi);
        }
        #pragma unroll
        for (int mf = 0; mf < 8; ++mf) {
            bf16x8 a = *(const bf16x8*)(base + (wr * 8 + mf) * 1024 + lane * 16);
            #pragma unroll
            for (int nf = 0; nf < NF; ++nf)
                acc[mf][nf] = __builtin_amdgcn_mfma_f32_16x16x32_bf16(a, bfr[nf], acc[mf][nf], 0, 0, 0);
        }
    };

    stage(0, 0);
    stage(1, 1);

    int bc = 0, bp = 2;
    for (int s = 0; s < 32; ++s) {
        if (s + 2 < 32) {
            stage(s + 2, bp);
            if constexpr (NF == 2) WAIT_VM(12); else WAIT_VM(10);
        } else if (s + 2 == 32) {
            if constexpr (NF == 2) WAIT_VM(6); else WAIT_VM(5);
        } else {
            WAIT_VM(0);
        }
        BARRIER();
        compute(bc);
        BARRIER();
        bc = (bc == 2) ? 0 : bc + 1;
        bp = (bp == 2) ? 0 : bp + 1;
    }

    #pragma unroll
    for (int mf = 0; mf < 8; ++mf) {
        int row = wr * 128 + mf * 16 + ((lane >> 4) << 2);
        #pragma unroll
        for (int nf = 0; nf < NF; ++nf) {
            int col = n0 + (wc * NF + nf) * 16 + (lane & 15);
            if (PRED && col >= N) continue;
            float bv = bias ? bias[col] : 0.0f;
            #pragma unroll
            for (int r = 0; r < 4; ++r)
                C[(size_t)(row + r) * ldc + col] = acc[mf][nf][r] + bv;
        }
    }
}

// Gather embedding row / convert hidden rows into bf16 fragment layout.
__global__ void prep_kernel(const int* __restrict__ ids, const float* __restrict__ hidden,
                            const float* __restrict__ emb,
                            short* __restrict__ x_frag, short* __restrict__ h_frag)
{
    const int m = blockIdx.x;
    const int which = blockIdx.y;
    const int j = threadIdx.x << 3;

    const float* src;
    short* dst;
    if (which == 0) { src = emb + (size_t)ids[m] * KDIM; dst = x_frag; }
    else {
        src = hidden + ((size_t)(which - 1) * 256 + m) * KDIM;
        dst = h_frag + (size_t)(which - 1) * 256 * KDIM;
    }
    f32x4 v0 = *(const f32x4*)(src + j);
    f32x4 v1 = *(const f32x4*)(src + j + 4);
    int mf = m >> 4, rr = m & 15, kf = j >> 5, g = (j >> 3) & 3;
    short* p = dst + (size_t)((mf * 32 + kf) * 64 + g * 16 + rr) * 8;
    short4v a, b;
    a.x = f2bf(v0.x); a.y = f2bf(v0.y); a.z = f2bf(v0.z); a.w = f2bf(v0.w);
    b.x = f2bf(v1.x); b.y = f2bf(v1.y); b.z = f2bf(v1.z); b.w = f2bf(v1.w);
    *(short4v*)p = a;
    *(short4v*)(p + 4) = b;
}

// GRU gates: h_new = (1-z)*n + z*h ; writes fp32 hidden_out and bf16 x fragments.
__global__ void gate_kernel(const float* __restrict__ gi, const float* __restrict__ gh,
                            const float* __restrict__ bi, const float* __restrict__ bh,
                            const float* __restrict__ hprev, float* __restrict__ hout,
                            short* __restrict__ x_frag)
{
    const int m = blockIdx.x;
    const int j = threadIdx.x << 3;
    const float* gim = gi + (size_t)m * 3072;
    const float* ghm = gh + (size_t)m * 3072;
    const float* hp = hprev + (size_t)m * KDIM;
    float* ho = hout + (size_t)m * KDIM;
    int mf = m >> 4, rr = m & 15, kf = j >> 5, g = (j >> 3) & 3;
    short* xp = x_frag + (size_t)((mf * 32 + kf) * 64 + g * 16 + rr) * 8;

    #pragma unroll
    for (int half = 0; half < 2; ++half) {
        int jj = j + half * 4;
        f32x4 vir = *(const f32x4*)(gim + jj);
        f32x4 viz = *(const f32x4*)(gim + 1024 + jj);
        f32x4 vin = *(const f32x4*)(gim + 2048 + jj);
        f32x4 vhr = *(const f32x4*)(ghm + jj);
        f32x4 vhz = *(const f32x4*)(ghm + 1024 + jj);
        f32x4 vhn = *(const f32x4*)(ghm + 2048 + jj);
        f32x4 bir = *(const f32x4*)(bi + jj);
        f32x4 biz = *(const f32x4*)(bi + 1024 + jj);
        f32x4 bin = *(const f32x4*)(bi + 2048 + jj);
        f32x4 bhr = *(const f32x4*)(bh + jj);
        f32x4 bhz = *(const f32x4*)(bh + 1024 + jj);
        f32x4 bhn = *(const f32x4*)(bh + 2048 + jj);
        f32x4 vh  = *(const f32x4*)(hp + jj);
        f32x4 outv;
        short4v xb;
        #pragma unroll
        for (int e = 0; e < 4; ++e) {
            float r = 1.f / (1.f + __expf(-(vir[e] + bir[e] + vhr[e] + bhr[e])));
            float z = 1.f / (1.f + __expf(-(viz[e] + biz[e] + vhz[e] + bhz[e])));
            float n = tanhf(vin[e] + bin[e] + r * (vhn[e] + bhn[e]));
            outv[e] = (1.f - z) * n + z * vh[e];
        }
        *(f32x4*)(ho + jj) = outv;
        xb.x = f2bf(outv[0]); xb.y = f2bf(outv[1]); xb.z = f2bf(outv[2]); xb.w = f2bf(outv[3]);
        *(short4v*)(xp + half * 4) = xb;
    }
}

extern "C" void kernel_launch(void* const* d_in, const int* in_sizes, int n_in,
                              void* d_out, int out_size, void* d_ws, size_t ws_size,
                              hipStream_t stream)
{
    const int*   ids    = (const int*)d_in[0];
    const float* hidden = (const float*)d_in[1];
    const float* emb    = (const float*)d_in[2];
    const float* w_ih   = (const float*)d_in[3];
    const float* w_hh   = (const float*)d_in[4];
    const float* b_ih   = (const float*)d_in[5];
    const float* b_hh   = (const float*)d_in[6];
    const float* dec_w  = (const float*)d_in[7];
    const float* dec_b  = (const float*)d_in[8];

    float* out = (float*)d_out;
    float* logits = out;                                  // [256][50000]
    float* hidden_out = out + (size_t)256 * 50000;        // [2][256][1024]

    short* x_frag = (short*)d_ws;                         // 256*1024 bf16
    short* h_frag = x_frag + 256 * 1024;                  // 2*256*1024 bf16
    float* gi = logits;                                   // scratch in logits region
    float* gh = logits + (size_t)256 * 3072;

    prep_kernel<<<dim3(256, 3), 128, 0, stream>>>(ids, hidden, emb, x_frag, h_frag);

    for (int l = 0; l < 2; ++l) {
        gemm_pipe<1, false><<<192, 256, 0, stream>>>(
            x_frag, w_ih + (size_t)l * 3072 * 1024, gi, 96,
            h_frag + (size_t)l * 256 * 1024, w_hh + (size_t)l * 3072 * 1024, gh,
            nullptr, 3072, 3072);
        gate_kernel<<<256, 128, 0, stream>>>(
            gi, gh, b_ih + (size_t)l * 3072, b_hh + (size_t)l * 3072,
            hidden + (size_t)l * 256 * 1024,
            hidden_out + (size_t)l * 256 * 1024, x_frag);
    }

    // decoder: 256x256 tiles, 196 blocks, 8 waves
    gemm_dec<<<196, 512, 0, stream>>>(x_frag, dec_w, logits, dec_b, 50000);
}

// Round 5
// 118.300 us; speedup vs baseline: 2.0523x; 1.0553x over previous
//
#include <hip/hip_runtime.h>

#define KDIM 1024

typedef __attribute__((ext_vector_type(8))) short bf16x8;
typedef __attribute__((ext_vector_type(4))) short short4v;
typedef __attribute__((ext_vector_type(4))) float f32x4;

__device__ __forceinline__ short f2bf(float f) {
    union { float f; unsigned u; } x; x.f = f;
    unsigned r = x.u + 0x7fffu + ((x.u >> 16) & 1u);   // RNE
    return (short)(r >> 16);
}

// 8x fp32 -> bf16x8 via v_cvt_pk_bf16_f32 (RNE on gfx950)
__device__ __forceinline__ bf16x8 cvt8(f32x4 a, f32x4 b) {
    union { unsigned u[4]; bf16x8 v; } r;
    asm("v_cvt_pk_bf16_f32 %0, %1, %2" : "=v"(r.u[0]) : "v"(a.x), "v"(a.y));
    asm("v_cvt_pk_bf16_f32 %0, %1, %2" : "=v"(r.u[1]) : "v"(a.z), "v"(a.w));
    asm("v_cvt_pk_bf16_f32 %0, %1, %2" : "=v"(r.u[2]) : "v"(b.x), "v"(b.y));
    asm("v_cvt_pk_bf16_f32 %0, %1, %2" : "=v"(r.u[3]) : "v"(b.z), "v"(b.w));
    return r.v;
}

__device__ __forceinline__ void gload16(const void* g, void* l) {
    __builtin_amdgcn_global_load_lds(
        (const __attribute__((address_space(1))) void*)g,
        (__attribute__((address_space(3))) void*)l, 16, 0, 0);
}

#define WAIT_VM(n) asm volatile("s_waitcnt vmcnt(" #n ")" ::: "memory")
#define BARRIER() do { asm volatile("" ::: "memory"); \
                       __builtin_amdgcn_s_barrier();  \
                       asm volatile("" ::: "memory"); } while (0)

// ---------------------------------------------------------------------------
// Decoder GEMM: C[m][n] = sum_k A[m][k]*W[n][k] + bias[n]
// M=256, K=1024, tile N=256, 196 blocks, 512 threads (8 waves: 2M x 4N).
// A: bf16 pre-fragmented, 16 KB/step, linear LDS (2 gload16/wave).
// W: fp32 row-major. Staged ROW-MAJOR in LDS: row r (tile-local col) at
//    byte r*128, chunk-swizzled: LDS slot (r, cc) holds global 16B chunk
//    (cc ^ (r&7)) of row n0+r. Global side of each gload16 = 8 rows x 128 B
//    contiguous (coalesced, no overfetch); LDS B-read spreads a quarter-wave
//    over all 32 banks (2 lanes/bank = free).
// Pipeline: 3-buffer ring, stage 2 ahead, counted vmcnt (12/6/0), 2 barriers.
// ---------------------------------------------------------------------------
__launch_bounds__(512, 1)
__global__ void gemm_dec(const short* __restrict__ A, const float* __restrict__ W,
                         float* __restrict__ C, const float* __restrict__ bias, int N)
{
    constexpr int BUFB = 49152;                 // A 16KB + W 32KB
    __shared__ __align__(1024) char lds[3 * BUFB];

    const int n0 = blockIdx.x * 256;
    const int t = threadIdx.x;
    const int lane = t & 63;
    const int w = t >> 6;       // 0..7
    const int wr = w >> 2;      // m half
    const int wc = w & 3;       // n quarter

    // --- staging source addresses ---
    // A: chunks 2w, 2w+1 (1KB each per step), lane-linear
    const short* gA[2];
    #pragma unroll
    for (int i = 0; i < 2; ++i)
        gA[i] = A + (size_t)(w * 2 + i) * 16384 + lane * 8;
    // W: window q = w*4+i covers rows q*8..q*8+7; lane = (row&7)*8 + cc
    const float* gW[4];
    int wdst[4];
    #pragma unroll
    for (int i = 0; i < 4; ++i) {
        int q = w * 4 + i;
        int row = q * 8 + (lane >> 3);
        int cc = lane & 7;
        int rowg = n0 + row;
        rowg = (rowg < N) ? rowg : (N - 1);
        gW[i] = W + (size_t)rowg * KDIM + ((cc ^ (row & 7)) << 2);
        wdst[i] = 16384 + q * 1024;              // wave-uniform LDS base
    }

    f32x4 acc[8][4];
    #pragma unroll
    for (int i = 0; i < 8; ++i)
        #pragma unroll
        for (int j = 0; j < 4; ++j)
            acc[i][j] = (f32x4){0.f, 0.f, 0.f, 0.f};

    auto stage = [&](int s, int buf) {
        char* base = lds + buf * BUFB;
        #pragma unroll
        for (int i = 0; i < 4; ++i)
            gload16(gW[i] + s * 32, base + wdst[i]);
        #pragma unroll
        for (int i = 0; i < 2; ++i)
            gload16(gA[i] + s * 512, base + (w * 2 + i) * 1024);
    };

    const int kc = lane >> 4;
    const int cl = lane & 15;

    auto compute = [&](int buf) {
        const char* base = lds + buf * BUFB;
        const char* Wb = base + 16384;
        bf16x8 bfr[4];
        #pragma unroll
        for (int nf = 0; nf < 4; ++nf) {
            int r = wc * 64 + nf * 16 + cl;
            const char* p = Wb + r * 128;
            f32x4 lo = *(const f32x4*)(p + (((kc * 2)     ^ (r & 7)) << 4));
            f32x4 hi = *(const f32x4*)(p + (((kc * 2 + 1) ^ (r & 7)) << 4));
            bfr[nf] = cvt8(lo, hi);
        }
        #pragma unroll
        for (int mf = 0; mf < 8; ++mf) {
            bf16x8 a = *(const bf16x8*)(base + (wr * 8 + mf) * 1024 + lane * 16);
            #pragma unroll
            for (int nf = 0; nf < 4; ++nf)
                acc[mf][nf] = __builtin_amdgcn_mfma_f32_16x16x32_bf16(a, bfr[nf], acc[mf][nf], 0, 0, 0);
        }
    };

    stage(0, 0);
    stage(1, 1);

    int bc = 0, bp = 2;
    for (int s = 0; s < 32; ++s) {
        if (s + 2 < 32) {
            stage(s + 2, bp);
            WAIT_VM(12);
        } else if (s + 2 == 32) {
            WAIT_VM(6);
        } else {
            WAIT_VM(0);
        }
        BARRIER();               // stage(s) visible to all waves
        compute(bc);
        BARRIER();               // buf bc fully read before re-staging
        bc = (bc == 2) ? 0 : bc + 1;
        bp = (bp == 2) ? 0 : bp + 1;
    }

    // epilogue: C/D layout col = lane&15, row = (lane>>4)*4 + reg
    #pragma unroll
    for (int mf = 0; mf < 8; ++mf) {
        int row = wr * 128 + mf * 16 + ((lane >> 4) << 2);
        #pragma unroll
        for (int nf = 0; nf < 4; ++nf) {
            int col = n0 + wc * 64 + nf * 16 + cl;
            if (col >= N) continue;
            float bv = bias[col];
            #pragma unroll
            for (int r = 0; r < 4; ++r)
                C[(size_t)(row + r) * N + col] = acc[mf][nf][r] + bv;
        }
    }
}

// ---------------------------------------------------------------------------
// GRU gemm (R3 structure, proven): tile N = 32*NF, 3-buf gload_lds ring.
// ---------------------------------------------------------------------------
template<int NF, bool PRED>
__launch_bounds__(256, 2)
__global__ void gemm_pipe(const short* __restrict__ A0, const float* __restrict__ W0,
                          float* __restrict__ C0, int nb0,
                          const short* __restrict__ A1, const float* __restrict__ W1,
                          float* __restrict__ C1,
                          const float* __restrict__ bias, int N, int ldc)
{
    constexpr int WBYTES = NF * 4096;
    constexpr int BUFB   = 16384 + WBYTES;
    __shared__ __align__(1024) char lds[3 * BUFB];

    const int bx = blockIdx.x;
    const short* A; const float* W; float* C; int n0;
    if (bx < nb0) { A = A0; W = W0; C = C0; n0 = bx * (32 * NF); }
    else          { A = A1; W = W1; C = C1; n0 = (bx - nb0) * (32 * NF); }

    const int t = threadIdx.x;
    const int lane = t & 63;
    const int w = t >> 6;
    const int wr = w >> 1;
    const int wc = w & 1;

    const float* gW[NF];
    #pragma unroll
    for (int i = 0; i < NF; ++i) {
        int sl = (i * 4 + w) * 64 + lane;
        int row = sl >> 3, cc = sl & 7;
        int rowg = n0 + row;
        if (PRED) rowg = (rowg < N) ? rowg : (N - 1);
        gW[i] = W + (size_t)rowg * KDIM + ((cc ^ (row & 7)) << 2);
    }
    const short* gA[4];
    #pragma unroll
    for (int j = 0; j < 4; ++j)
        gA[j] = A + (size_t)(j * 4 + w) * 16384 + lane * 8;

    f32x4 acc[8][NF];
    #pragma unroll
    for (int i = 0; i < 8; ++i)
        #pragma unroll
        for (int j = 0; j < NF; ++j)
            acc[i][j] = (f32x4){0.f, 0.f, 0.f, 0.f};

    auto stage = [&](int s, int buf) {
        char* base = lds + buf * BUFB;
        #pragma unroll
        for (int i = 0; i < NF; ++i)
            gload16(gW[i] + s * 32, base + 16384 + (i * 4 + w) * 1024);
        #pragma unroll
        for (int j = 0; j < 4; ++j)
            gload16(gA[j] + s * 512, base + (j * 4 + w) * 1024);
    };

    auto compute = [&](int buf) {
        const char* base = lds + buf * BUFB;
        const char* Wb = base + 16384;
        bf16x8 bfr[NF];
        #pragma unroll
        for (int nf = 0; nf < NF; ++nf) {
            int row = (wc * NF + nf) * 16 + (lane & 15);
            int c0 = (lane >> 4) << 1;
            f32x4 lo = *(const f32x4*)(Wb + row * 128 + ((c0 ^ (row & 7)) << 4));
            f32x4 hi = *(const f32x4*)(Wb + row * 128 + (((c0 + 1) ^ (row & 7)) << 4));
            bfr[nf] = cvt8(lo, hi);
        }
        #pragma unroll
        for (int mf = 0; mf < 8; ++mf) {
            bf16x8 a = *(const bf16x8*)(base + (wr * 8 + mf) * 1024 + lane * 16);
            #pragma unroll
            for (int nf = 0; nf < NF; ++nf)
                acc[mf][nf] = __builtin_amdgcn_mfma_f32_16x16x32_bf16(a, bfr[nf], acc[mf][nf], 0, 0, 0);
        }
    };

    stage(0, 0);
    stage(1, 1);

    int bc = 0, bp = 2;
    for (int s = 0; s < 32; ++s) {
        if (s + 2 < 32) {
            stage(s + 2, bp);
            if constexpr (NF == 2) WAIT_VM(12); else WAIT_VM(10);
        } else if (s + 2 == 32) {
            if constexpr (NF == 2) WAIT_VM(6); else WAIT_VM(5);
        } else {
            WAIT_VM(0);
        }
        BARRIER();
        compute(bc);
        BARRIER();
        bc = (bc == 2) ? 0 : bc + 1;
        bp = (bp == 2) ? 0 : bp + 1;
    }

    #pragma unroll
    for (int mf = 0; mf < 8; ++mf) {
        int row = wr * 128 + mf * 16 + ((lane >> 4) << 2);
        #pragma unroll
        for (int nf = 0; nf < NF; ++nf) {
            int col = n0 + (wc * NF + nf) * 16 + (lane & 15);
            if (PRED && col >= N) continue;
            float bv = bias ? bias[col] : 0.0f;
            #pragma unroll
            for (int r = 0; r < 4; ++r)
                C[(size_t)(row + r) * ldc + col] = acc[mf][nf][r] + bv;
        }
    }
}

// Gather embedding row / convert hidden rows into bf16 fragment layout.
__global__ void prep_kernel(const int* __restrict__ ids, const float* __restrict__ hidden,
                            const float* __restrict__ emb,
                            short* __restrict__ x_frag, short* __restrict__ h_frag)
{
    const int m = blockIdx.x;
    const int which = blockIdx.y;
    const int j = threadIdx.x << 3;

    const float* src;
    short* dst;
    if (which == 0) { src = emb + (size_t)ids[m] * KDIM; dst = x_frag; }
    else {
        src = hidden + ((size_t)(which - 1) * 256 + m) * KDIM;
        dst = h_frag + (size_t)(which - 1) * 256 * KDIM;
    }
    f32x4 v0 = *(const f32x4*)(src + j);
    f32x4 v1 = *(const f32x4*)(src + j + 4);
    int mf = m >> 4, rr = m & 15, kf = j >> 5, g = (j >> 3) & 3;
    short* p = dst + (size_t)((mf * 32 + kf) * 64 + g * 16 + rr) * 8;
    short4v a, b;
    a.x = f2bf(v0.x); a.y = f2bf(v0.y); a.z = f2bf(v0.z); a.w = f2bf(v0.w);
    b.x = f2bf(v1.x); b.y = f2bf(v1.y); b.z = f2bf(v1.z); b.w = f2bf(v1.w);
    *(short4v*)p = a;
    *(short4v*)(p + 4) = b;
}

// GRU gates: h_new = (1-z)*n + z*h ; writes fp32 hidden_out and bf16 x fragments.
__global__ void gate_kernel(const float* __restrict__ gi, const float* __restrict__ gh,
                            const float* __restrict__ bi, const float* __restrict__ bh,
                            const float* __restrict__ hprev, float* __restrict__ hout,
                            short* __restrict__ x_frag)
{
    const int m = blockIdx.x;
    const int j = threadIdx.x << 3;
    const float* gim = gi + (size_t)m * 3072;
    const float* ghm = gh + (size_t)m * 3072;
    const float* hp = hprev + (size_t)m * KDIM;
    float* ho = hout + (size_t)m * KDIM;
    int mf = m >> 4, rr = m & 15, kf = j >> 5, g = (j >> 3) & 3;
    short* xp = x_frag + (size_t)((mf * 32 + kf) * 64 + g * 16 + rr) * 8;

    #pragma unroll
    for (int half = 0; half < 2; ++half) {
        int jj = j + half * 4;
        f32x4 vir = *(const f32x4*)(gim + jj);
        f32x4 viz = *(const f32x4*)(gim + 1024 + jj);
        f32x4 vin = *(const f32x4*)(gim + 2048 + jj);
        f32x4 vhr = *(const f32x4*)(ghm + jj);
        f32x4 vhz = *(const f32x4*)(ghm + 1024 + jj);
        f32x4 vhn = *(const f32x4*)(ghm + 2048 + jj);
        f32x4 bir = *(const f32x4*)(bi + jj);
        f32x4 biz = *(const f32x4*)(bi + 1024 + jj);
        f32x4 bin = *(const f32x4*)(bi + 2048 + jj);
        f32x4 bhr = *(const f32x4*)(bh + jj);
        f32x4 bhz = *(const f32x4*)(bh + 1024 + jj);
        f32x4 bhn = *(const f32x4*)(bh + 2048 + jj);
        f32x4 vh  = *(const f32x4*)(hp + jj);
        f32x4 outv;
        short4v xb;
        #pragma unroll
        for (int e = 0; e < 4; ++e) {
            float r = 1.f / (1.f + __expf(-(vir[e] + bir[e] + vhr[e] + bhr[e])));
            float z = 1.f / (1.f + __expf(-(viz[e] + biz[e] + vhz[e] + bhz[e])));
            float n = tanhf(vin[e] + bin[e] + r * (vhn[e] + bhn[e]));
            outv[e] = (1.f - z) * n + z * vh[e];
        }
        *(f32x4*)(ho + jj) = outv;
        xb.x = f2bf(outv[0]); xb.y = f2bf(outv[1]); xb.z = f2bf(outv[2]); xb.w = f2bf(outv[3]);
        *(short4v*)(xp + half * 4) = xb;
    }
}

extern "C" void kernel_launch(void* const* d_in, const int* in_sizes, int n_in,
                              void* d_out, int out_size, void* d_ws, size_t ws_size,
                              hipStream_t stream)
{
    const int*   ids    = (const int*)d_in[0];
    const float* hidden = (const float*)d_in[1];
    const float* emb    = (const float*)d_in[2];
    const float* w_ih   = (const float*)d_in[3];
    const float* w_hh   = (const float*)d_in[4];
    const float* b_ih   = (const float*)d_in[5];
    const float* b_hh   = (const float*)d_in[6];
    const float* dec_w  = (const float*)d_in[7];
    const float* dec_b  = (const float*)d_in[8];

    float* out = (float*)d_out;
    float* logits = out;                                  // [256][50000]
    float* hidden_out = out + (size_t)256 * 50000;        // [2][256][1024]

    short* x_frag = (short*)d_ws;                         // 256*1024 bf16
    short* h_frag = x_frag + 256 * 1024;                  // 2*256*1024 bf16
    float* gi = logits;                                   // scratch in logits region
    float* gh = logits + (size_t)256 * 3072;

    prep_kernel<<<dim3(256, 3), 128, 0, stream>>>(ids, hidden, emb, x_frag, h_frag);

    for (int l = 0; l < 2; ++l) {
        gemm_pipe<1, false><<<192, 256, 0, stream>>>(
            x_frag, w_ih + (size_t)l * 3072 * 1024, gi, 96,
            h_frag + (size_t)l * 256 * 1024, w_hh + (size_t)l * 3072 * 1024, gh,
            nullptr, 3072, 3072);
        gate_kernel<<<256, 128, 0, stream>>>(
            gi, gh, b_ih + (size_t)l * 3072, b_hh + (size_t)l * 3072,
            hidden + (size_t)l * 256 * 1024,
            hidden_out + (size_t)l * 256 * 1024, x_frag);
    }

    // decoder: 256x256 tiles, 196 blocks, 8 waves, coalesced W staging
    gemm_dec<<<196, 512, 0, stream>>>(x_frag, dec_w, logits, dec_b, 50000);
}